// Round 1
// baseline (37.262 us; speedup 1.0000x reference)
//
#include <hip/hip_runtime.h>

#define BB 256      // drug pairs
#define NP 40       // atoms per graph
#define HH 128      // hidden dim
#define NPAIR (NP*NP)  // 1600
#define PST 132     // padded LDS row stride (floats); 132*4=528 B, 16B-aligned
#define NT 512      // threads per block

__global__ __launch_bounds__(NT) void ddi_fused(
    const float* __restrict__ h1, const float* __restrict__ h2,
    const float* __restrict__ W1, const float* __restrict__ b1,
    const float* __restrict__ W2, const float* __restrict__ b2,
    float* __restrict__ out)
{
    const int b = blockIdx.x;
    const int t = threadIdx.x;

    // Phase-1 A tiles alias phase-2 P tiles (disjoint lifetimes, barrier between).
    __shared__ __align__(16) char smemPA[2 * NP * PST * 4];   // 42240 B
    __shared__ __align__(16) float sE[NPAIR];                 // 6400 B
    __shared__ __align__(16) float sW2[HH];                   // 512 B
    __shared__ float sRed[NT/64];
    __shared__ float sCL;   // (b2 + sum(w2)) * log2(e)
    __shared__ float sRZ;   // 1/Z

    float* sA1 = (float*)smemPA;          // [NP][HH] during phase 1
    float* sA2 = sA1 + NP*HH;
    float* sP1 = (float*)smemPA;          // [NP][PST] during phase 2 (alias)
    float* sP2 = sP1 + NP*PST;

    // ---- Phase 0: stage A tiles (coalesced float4) + w2 ----
    const float4* g1 = (const float4*)(h1 + (size_t)b * NP * HH);
    const float4* g2 = (const float4*)(h2 + (size_t)b * NP * HH);
    for (int idx = t; idx < NP*HH/4; idx += NT) {
        ((float4*)sA1)[idx] = g1[idx];
        ((float4*)sA2)[idx] = g2[idx];
    }
    if (t < HH) sW2[t] = W2[t];
    __syncthreads();

    // ---- Phase 1: projections. thread -> (col h, rows r0..r0+9) ----
    const int h  = t & (HH-1);
    const int rw = t >> 7;          // 0..3
    const int r0 = rw * 10;

    if (t == 0) {  // constant C*log2e, computed once while others do proj
        float c = b2[0];
        for (int hh = 0; hh < HH; ++hh) c += sW2[hh];
        sCL = c * 1.44269504088896340736f;
    }

    float acc1[10], acc2[10];
    #pragma unroll
    for (int r = 0; r < 10; ++r) { acc1[r] = 0.f; acc2[r] = 0.f; }

    // manual 1-deep prefetch of W columns to cover global latency
    float wa[4], wb[4], nwa[4], nwb[4];
    #pragma unroll
    for (int k = 0; k < 4; ++k) {
        wa[k] = W1[k*HH + h];
        wb[k] = W1[(k+HH)*HH + h];
    }
    for (int d0 = 0; d0 < HH; d0 += 4) {
        if (d0 + 4 < HH) {
            #pragma unroll
            for (int k = 0; k < 4; ++k) {
                nwa[k] = W1[(d0+4+k)*HH + h];
                nwb[k] = W1[(d0+4+k+HH)*HH + h];
            }
        }
        #pragma unroll
        for (int r = 0; r < 10; ++r) {
            float4 a1v = *(const float4*)(sA1 + (r0+r)*HH + d0);
            float4 a2v = *(const float4*)(sA2 + (r0+r)*HH + d0);
            acc1[r] = fmaf(a1v.x, wa[0], acc1[r]);
            acc1[r] = fmaf(a1v.y, wa[1], acc1[r]);
            acc1[r] = fmaf(a1v.z, wa[2], acc1[r]);
            acc1[r] = fmaf(a1v.w, wa[3], acc1[r]);
            acc2[r] = fmaf(a2v.x, wb[0], acc2[r]);
            acc2[r] = fmaf(a2v.y, wb[1], acc2[r]);
            acc2[r] = fmaf(a2v.z, wb[2], acc2[r]);
            acc2[r] = fmaf(a2v.w, wb[3], acc2[r]);
        }
        #pragma unroll
        for (int k = 0; k < 4; ++k) { wa[k] = nwa[k]; wb[k] = nwb[k]; }
    }

    // fold b1 and the 2*log2(e) tanh scale into P
    const float K = 2.88539008177792681472f;   // 2*log2(e)
    const float bh = b1[h];
    float p1v[10], p2v[10];
    #pragma unroll
    for (int r = 0; r < 10; ++r) {
        p1v[r] = (acc1[r] + bh) * K;
        p2v[r] = acc2[r] * K;
    }

    __syncthreads();   // all sA reads done before aliasing write

    #pragma unroll
    for (int r = 0; r < 10; ++r) {
        sP1[(r0+r)*PST + h] = p1v[r];
        sP2[(r0+r)*PST + h] = p2v[r];
    }
    __syncthreads();

    // ---- Phase 2: 1600 pair scores; tanh(x) = 1 - 2/(exp2(x')+1), x'=2x*log2e ----
    float lsum = 0.f;
    const float CL = sCL;
    for (int pair = t; pair < NPAIR; pair += NT) {
        const int i = pair / NP;
        const int j = pair - i * NP;
        const float* p1r = sP1 + i * PST;
        const float* p2r = sP2 + j * PST;
        float acc = 0.f;   // = sum_h w2[h] / (e^{2x}+1)
        #pragma unroll 4
        for (int h0 = 0; h0 < HH; h0 += 4) {
            float4 x1 = *(const float4*)(p1r + h0);
            float4 x2 = *(const float4*)(p2r + h0);
            float4 wv = *(const float4*)(sW2 + h0);
            float e0 = __builtin_amdgcn_exp2f(x1.x + x2.x);
            float e1 = __builtin_amdgcn_exp2f(x1.y + x2.y);
            float e2 = __builtin_amdgcn_exp2f(x1.z + x2.z);
            float e3 = __builtin_amdgcn_exp2f(x1.w + x2.w);
            acc = fmaf(wv.x, __builtin_amdgcn_rcpf(e0 + 1.f), acc);
            acc = fmaf(wv.y, __builtin_amdgcn_rcpf(e1 + 1.f), acc);
            acc = fmaf(wv.z, __builtin_amdgcn_rcpf(e2 + 1.f), acc);
            acc = fmaf(wv.w, __builtin_amdgcn_rcpf(e3 + 1.f), acc);
        }
        // logit = C - 2*acc ; unnormalized prob = exp2(CL - K*acc)
        float pu = __builtin_amdgcn_exp2f(fmaf(acc, -K, CL));
        sE[pair] = pu;
        lsum += pu;
    }

    // ---- block reduction for Z ----
    #pragma unroll
    for (int off = 32; off > 0; off >>= 1) lsum += __shfl_down(lsum, off, 64);
    const int lane = t & 63;
    const int wvi  = t >> 6;
    if (lane == 0) sRed[wvi] = lsum;
    __syncthreads();
    if (t == 0) {
        float Z = 0.f;
        #pragma unroll
        for (int w = 0; w < NT/64; ++w) Z += sRed[w];
        sRZ = 1.0f / Z;
    }
    __syncthreads();
    const float rZ = sRZ;

    // ---- Phase 3: row sums (attn1) and col sums (attn2) ----
    if (t < NP) {
        float s = 0.f;
        #pragma unroll
        for (int j = 0; j < NP; ++j) s += sE[t*NP + j];
        out[b*NP + t] = s * rZ;
    } else if (t >= 64 && t < 64 + NP) {
        const int j = t - 64;
        float s = 0.f;
        #pragma unroll
        for (int i = 0; i < NP; ++i) s += sE[i*NP + j];
        out[BB*NP + b*NP + j] = s * rZ;
    }
}

extern "C" void kernel_launch(void* const* d_in, const int* in_sizes, int n_in,
                              void* d_out, int out_size, void* d_ws, size_t ws_size,
                              hipStream_t stream) {
    const float* h1 = (const float*)d_in[0];
    const float* h2 = (const float*)d_in[1];
    // d_in[2], d_in[3] are batch1/batch2 (unused: equal-sized sorted segments)
    const float* W1 = (const float*)d_in[4];
    const float* b1 = (const float*)d_in[5];
    const float* W2 = (const float*)d_in[6];
    const float* b2 = (const float*)d_in[7];
    float* out = (float*)d_out;

    hipLaunchKernelGGL(ddi_fused, dim3(BB), dim3(NT), 0, stream,
                       h1, h2, W1, b1, W2, b2, out);
}

// Round 2
// 35.602 us; speedup vs baseline: 1.0466x; 1.0466x over previous
//
#include <hip/hip_runtime.h>

#define BB 256      // drug pairs
#define NP 40       // atoms per graph
#define HH 128      // hidden dim
#define NPAIR (NP*NP)  // 1600
#define PST 132     // padded LDS row stride (floats); 132*4=528 B, 16B-aligned
#define NT 1024     // threads per block (16 waves/CU)

__global__ __launch_bounds__(NT) void ddi_fused(
    const float* __restrict__ h1, const float* __restrict__ h2,
    const float* __restrict__ W1, const float* __restrict__ b1,
    const float* __restrict__ W2, const float* __restrict__ b2,
    float* __restrict__ out)
{
    const int b = blockIdx.x;
    const int t = threadIdx.x;

    // Phase-1 A tiles alias phase-2 P tiles (disjoint lifetimes, barrier between).
    __shared__ __align__(16) char smemPA[2 * NP * PST * 4];   // 42240 B
    __shared__ __align__(16) float sE[NPAIR];                 // 6400 B
    __shared__ __align__(16) float sW2[HH];                   // 512 B
    __shared__ float sRed[NT/64];
    __shared__ float sCL;   // (b2 + sum(w2)) * log2(e)
    __shared__ float sRZ;   // 1/Z

    float* sA1 = (float*)smemPA;          // [NP][HH] during phase 1
    float* sA2 = sA1 + NP*HH;
    float* sP1 = (float*)smemPA;          // [NP][PST] during phase 2 (alias)
    float* sP2 = sP1 + NP*PST;

    // ---- Phase 0: stage A tiles (coalesced float4) + w2 + CL constant ----
    const float4* g1 = (const float4*)(h1 + (size_t)b * NP * HH);
    const float4* g2 = (const float4*)(h2 + (size_t)b * NP * HH);
    for (int idx = t; idx < NP*HH/4; idx += NT) {
        ((float4*)sA1)[idx] = g1[idx];
        ((float4*)sA2)[idx] = g2[idx];
    }
    if (t < HH) sW2[t] = W2[t];
    if (t < 64) {   // wave 0: CL = (b2 + sum(w2)) * log2e via shuffle reduce
        float c = W2[t] + W2[t + 64];
        #pragma unroll
        for (int off = 32; off > 0; off >>= 1) c += __shfl_down(c, off, 64);
        if (t == 0) sCL = (c + b2[0]) * 1.44269504088896340736f;
    }
    __syncthreads();

    // ---- Phase 1: projections. t<512 -> P1, t>=512 -> P2; (col h, 10 rows) ----
    const int m  = t >> 9;              // 0: P1, 1: P2
    const int h  = t & (HH-1);
    const int r0 = ((t >> 7) & 3) * 10;
    const float* sA   = m ? sA2 : sA1;
    const float* Wcol = W1 + (size_t)m * HH * HH + h;

    float acc[10];
    #pragma unroll
    for (int r = 0; r < 10; ++r) acc[r] = 0.f;

    // 1-deep prefetch of W column quads to cover global latency
    float w[4], nw[4];
    #pragma unroll
    for (int k = 0; k < 4; ++k) w[k] = Wcol[k*HH];
    for (int d0 = 0; d0 < HH; d0 += 4) {
        if (d0 + 4 < HH) {
            #pragma unroll
            for (int k = 0; k < 4; ++k) nw[k] = Wcol[(d0+4+k)*HH];
        }
        #pragma unroll
        for (int r = 0; r < 10; ++r) {
            float4 a = *(const float4*)(sA + (r0+r)*HH + d0);   // wave-uniform addr: LDS broadcast
            acc[r] = fmaf(a.x, w[0], acc[r]);
            acc[r] = fmaf(a.y, w[1], acc[r]);
            acc[r] = fmaf(a.z, w[2], acc[r]);
            acc[r] = fmaf(a.w, w[3], acc[r]);
        }
        #pragma unroll
        for (int k = 0; k < 4; ++k) w[k] = nw[k];
    }

    // fold b1 (into P1 only) and the 2*log2(e) tanh scale
    const float K = 2.88539008177792681472f;   // 2*log2(e)
    const float addb = m ? 0.f : b1[h];
    float pv[10];
    #pragma unroll
    for (int r = 0; r < 10; ++r) pv[r] = (acc[r] + addb) * K;

    __syncthreads();   // all sA reads done before aliasing write

    float* sPd = m ? sP2 : sP1;
    #pragma unroll
    for (int r = 0; r < 10; ++r) sPd[(r0+r)*PST + h] = pv[r];
    __syncthreads();

    // ---- Phase 2: thread t<800 owns pairs (i,j0),(i,j0+1): x1/w2 reuse ----
    float lsum = 0.f;
    const float CL = sCL;
    if (t < 800) {
        const int i  = t / 20;
        const int j0 = (t % 20) * 2;
        const float* p1r = sP1 + i  * PST;
        const float* p2a = sP2 + j0 * PST;
        const float* p2b = p2a + PST;
        float acca = 0.f, accb = 0.f;   // = sum_h w2[h] / (e^{2x}+1)
        #pragma unroll 2
        for (int h0 = 0; h0 < HH; h0 += 4) {
            float4 x1 = *(const float4*)(p1r + h0);
            float4 wv = *(const float4*)(sW2 + h0);
            float4 xa = *(const float4*)(p2a + h0);
            float4 xb = *(const float4*)(p2b + h0);
            float ea0 = __builtin_amdgcn_exp2f(x1.x + xa.x);
            float ea1 = __builtin_amdgcn_exp2f(x1.y + xa.y);
            float ea2 = __builtin_amdgcn_exp2f(x1.z + xa.z);
            float ea3 = __builtin_amdgcn_exp2f(x1.w + xa.w);
            float eb0 = __builtin_amdgcn_exp2f(x1.x + xb.x);
            float eb1 = __builtin_amdgcn_exp2f(x1.y + xb.y);
            float eb2 = __builtin_amdgcn_exp2f(x1.z + xb.z);
            float eb3 = __builtin_amdgcn_exp2f(x1.w + xb.w);
            acca = fmaf(wv.x, __builtin_amdgcn_rcpf(ea0 + 1.f), acca);
            acca = fmaf(wv.y, __builtin_amdgcn_rcpf(ea1 + 1.f), acca);
            acca = fmaf(wv.z, __builtin_amdgcn_rcpf(ea2 + 1.f), acca);
            acca = fmaf(wv.w, __builtin_amdgcn_rcpf(ea3 + 1.f), acca);
            accb = fmaf(wv.x, __builtin_amdgcn_rcpf(eb0 + 1.f), accb);
            accb = fmaf(wv.y, __builtin_amdgcn_rcpf(eb1 + 1.f), accb);
            accb = fmaf(wv.z, __builtin_amdgcn_rcpf(eb2 + 1.f), accb);
            accb = fmaf(wv.w, __builtin_amdgcn_rcpf(eb3 + 1.f), accb);
        }
        // logit = C - 2*acc ; unnormalized prob = exp2(CL - K*acc)
        float pu0 = __builtin_amdgcn_exp2f(fmaf(acca, -K, CL));
        float pu1 = __builtin_amdgcn_exp2f(fmaf(accb, -K, CL));
        *(float2*)(sE + i*NP + j0) = make_float2(pu0, pu1);
        lsum = pu0 + pu1;
    }

    // ---- block reduction for Z ----
    #pragma unroll
    for (int off = 32; off > 0; off >>= 1) lsum += __shfl_down(lsum, off, 64);
    if ((t & 63) == 0) sRed[t >> 6] = lsum;
    __syncthreads();
    if (t == 0) {
        float Z = 0.f;
        #pragma unroll
        for (int wv = 0; wv < NT/64; ++wv) Z += sRed[wv];
        sRZ = 1.0f / Z;
    }
    __syncthreads();
    const float rZ = sRZ;

    // ---- Phase 3: row sums (attn1) and col sums (attn2) ----
    if (t < NP) {
        float s = 0.f;
        #pragma unroll
        for (int q = 0; q < NP/4; ++q) {
            float4 v = *(const float4*)(sE + t*NP + q*4);
            s += v.x + v.y + v.z + v.w;
        }
        out[b*NP + t] = s * rZ;
    } else if (t >= 64 && t < 64 + NP) {
        const int j = t - 64;
        float s = 0.f;
        #pragma unroll
        for (int i2 = 0; i2 < NP; ++i2) s += sE[i2*NP + j];
        out[BB*NP + b*NP + j] = s * rZ;
    }
}

extern "C" void kernel_launch(void* const* d_in, const int* in_sizes, int n_in,
                              void* d_out, int out_size, void* d_ws, size_t ws_size,
                              hipStream_t stream) {
    const float* h1 = (const float*)d_in[0];
    const float* h2 = (const float*)d_in[1];
    // d_in[2], d_in[3] are batch1/batch2 (unused: equal-sized sorted segments)
    const float* W1 = (const float*)d_in[4];
    const float* b1 = (const float*)d_in[5];
    const float* W2 = (const float*)d_in[6];
    const float* b2 = (const float*)d_in[7];
    float* out = (float*)d_out;

    hipLaunchKernelGGL(ddi_fused, dim3(BB), dim3(NT), 0, stream,
                       h1, h2, W1, b1, W2, b2, out);
}

// Round 3
// 33.239 us; speedup vs baseline: 1.1210x; 1.0711x over previous
//
#include <hip/hip_runtime.h>

#define BB 256      // drug pairs
#define NP 40       // atoms per graph
#define HH 128      // hidden dim
#define NPAIR (NP*NP)  // 1600
#define PST 132     // padded LDS row stride (floats); 132*4=528 B, 16B-aligned
#define NT 1024     // threads per block (16 waves/CU)

__global__ __launch_bounds__(NT) void ddi_fused(
    const float* __restrict__ h1, const float* __restrict__ h2,
    const float* __restrict__ W1, const float* __restrict__ b1,
    const float* __restrict__ W2, const float* __restrict__ b2,
    float* __restrict__ out)
{
    const int b = blockIdx.x;
    const int t = threadIdx.x;

    // Phase-1 A tiles alias phase-2 T tiles (disjoint lifetimes, barrier between).
    __shared__ __align__(16) char smemPA[2 * NP * PST * 4];   // 42240 B
    __shared__ __align__(16) float sE[NPAIR];                 // 6400 B
    __shared__ __align__(16) float sW2[HH];                   // 512 B
    __shared__ float sRed[NT/64];
    __shared__ float sCL;   // b2 * log2(e)
    __shared__ float sRZ;   // 1/Z

    float* sA1 = (float*)smemPA;          // [NP][HH] during phase 1
    float* sA2 = sA1 + NP*HH;
    float* sT1 = (float*)smemPA;          // [NP][PST] tanh(p1+b1) (alias)
    float* sT2 = sT1 + NP*PST;            // [NP][PST] tanh(p2)

    // ---- Phase 0: stage A tiles (coalesced float4) + w2 + CL ----
    const float4* g1 = (const float4*)(h1 + (size_t)b * NP * HH);
    const float4* g2 = (const float4*)(h2 + (size_t)b * NP * HH);
    for (int idx = t; idx < NP*HH/4; idx += NT) {
        ((float4*)sA1)[idx] = g1[idx];
        ((float4*)sA2)[idx] = g2[idx];
    }
    if (t < HH) sW2[t] = W2[t];
    if (t == 0) sCL = b2[0] * 1.44269504088896340736f;
    __syncthreads();

    // ---- Phase 1: projections. t<512 -> T1, t>=512 -> T2; (col h, 10 rows) ----
    const int m  = t >> 9;              // 0: T1, 1: T2
    const int h  = t & (HH-1);
    const int r0 = ((t >> 7) & 3) * 10;
    const float* sA   = m ? sA2 : sA1;
    const float* Wcol = W1 + (size_t)m * HH * HH + h;

    float acc[10];
    #pragma unroll
    for (int r = 0; r < 10; ++r) acc[r] = 0.f;

    // 1-deep prefetch of W column quads to cover global latency
    float w[4], nw[4];
    #pragma unroll
    for (int k = 0; k < 4; ++k) w[k] = Wcol[k*HH];
    for (int d0 = 0; d0 < HH; d0 += 4) {
        if (d0 + 4 < HH) {
            #pragma unroll
            for (int k = 0; k < 4; ++k) nw[k] = Wcol[(d0+4+k)*HH];
        }
        #pragma unroll
        for (int r = 0; r < 10; ++r) {
            float4 a = *(const float4*)(sA + (r0+r)*HH + d0);   // wave-uniform addr: LDS broadcast
            acc[r] = fmaf(a.x, w[0], acc[r]);
            acc[r] = fmaf(a.y, w[1], acc[r]);
            acc[r] = fmaf(a.z, w[2], acc[r]);
            acc[r] = fmaf(a.w, w[3], acc[r]);
        }
        #pragma unroll
        for (int k = 0; k < 4; ++k) w[k] = nw[k];
    }

    // tanh(acc [+ b1]) via exp2: t = 1 - 2/(exp2(2x*log2e)+1)
    const float K = 2.88539008177792681472f;   // 2*log2(e)
    const float addb = m ? 0.f : b1[h];
    float tv[10];
    #pragma unroll
    for (int r = 0; r < 10; ++r) {
        float e = __builtin_amdgcn_exp2f((acc[r] + addb) * K);
        tv[r] = 1.f - 2.f * __builtin_amdgcn_rcpf(e + 1.f);
    }

    __syncthreads();   // all sA reads done before aliasing write

    float* sTd = m ? sT2 : sT1;
    #pragma unroll
    for (int r = 0; r < 10; ++r) sTd[(r0+r)*PST + h] = tv[r];
    __syncthreads();

    // ---- Phase 2: thread t<800 owns pairs (i,j),(i,j+20); tanh-add identity ----
    // hidden tanh = (t1+t2)/(1+t1*t2); logit = b2 + sum_h w2[h]*that
    float lsum = 0.f;
    const float CL = sCL;
    if (t < 800) {
        const int i = t / 20;
        const int j = t % 20;
        const float* t1r = sT1 + i * PST;
        const float* t2a = sT2 + j * PST;
        const float* t2b = t2a + 20 * PST;
        float acca = 0.f, accb = 0.f;
        #pragma unroll 4
        for (int h0 = 0; h0 < HH; h0 += 4) {
            float4 x1 = *(const float4*)(t1r + h0);
            float4 wv = *(const float4*)(sW2 + h0);
            float4 xa = *(const float4*)(t2a + h0);
            float4 xb = *(const float4*)(t2b + h0);
            float na0 = x1.x + xa.x, da0 = fmaf(x1.x, xa.x, 1.f);
            float na1 = x1.y + xa.y, da1 = fmaf(x1.y, xa.y, 1.f);
            float na2 = x1.z + xa.z, da2 = fmaf(x1.z, xa.z, 1.f);
            float na3 = x1.w + xa.w, da3 = fmaf(x1.w, xa.w, 1.f);
            float nb0 = x1.x + xb.x, db0 = fmaf(x1.x, xb.x, 1.f);
            float nb1 = x1.y + xb.y, db1 = fmaf(x1.y, xb.y, 1.f);
            float nb2 = x1.z + xb.z, db2 = fmaf(x1.z, xb.z, 1.f);
            float nb3 = x1.w + xb.w, db3 = fmaf(x1.w, xb.w, 1.f);
            acca = fmaf(wv.x * na0, __builtin_amdgcn_rcpf(da0), acca);
            acca = fmaf(wv.y * na1, __builtin_amdgcn_rcpf(da1), acca);
            acca = fmaf(wv.z * na2, __builtin_amdgcn_rcpf(da2), acca);
            acca = fmaf(wv.w * na3, __builtin_amdgcn_rcpf(da3), acca);
            accb = fmaf(wv.x * nb0, __builtin_amdgcn_rcpf(db0), accb);
            accb = fmaf(wv.y * nb1, __builtin_amdgcn_rcpf(db1), accb);
            accb = fmaf(wv.z * nb2, __builtin_amdgcn_rcpf(db2), accb);
            accb = fmaf(wv.w * nb3, __builtin_amdgcn_rcpf(db3), accb);
        }
        // unnormalized prob = exp2((logit)*log2e) = exp2(acc*log2e + CL)
        const float L2E = 1.44269504088896340736f;
        float pu0 = __builtin_amdgcn_exp2f(fmaf(acca, L2E, CL));
        float pu1 = __builtin_amdgcn_exp2f(fmaf(accb, L2E, CL));
        sE[i*NP + j]      = pu0;
        sE[i*NP + j + 20] = pu1;
        lsum = pu0 + pu1;
    }

    // ---- block reduction for Z ----
    #pragma unroll
    for (int off = 32; off > 0; off >>= 1) lsum += __shfl_down(lsum, off, 64);
    if ((t & 63) == 0) sRed[t >> 6] = lsum;
    __syncthreads();
    if (t == 0) {
        float Z = 0.f;
        #pragma unroll
        for (int wv = 0; wv < NT/64; ++wv) Z += sRed[wv];
        sRZ = 1.0f / Z;
    }
    __syncthreads();
    const float rZ = sRZ;

    // ---- Phase 3: row sums (attn1) and col sums (attn2) ----
    if (t < NP) {
        float s = 0.f;
        #pragma unroll
        for (int q = 0; q < NP/4; ++q) {
            float4 v = *(const float4*)(sE + t*NP + q*4);
            s += v.x + v.y + v.z + v.w;
        }
        out[b*NP + t] = s * rZ;
    } else if (t >= 64 && t < 64 + NP) {
        const int j = t - 64;
        float s = 0.f;
        #pragma unroll
        for (int i2 = 0; i2 < NP; ++i2) s += sE[i2*NP + j];
        out[BB*NP + b*NP + j] = s * rZ;
    }
}

extern "C" void kernel_launch(void* const* d_in, const int* in_sizes, int n_in,
                              void* d_out, int out_size, void* d_ws, size_t ws_size,
                              hipStream_t stream) {
    const float* h1 = (const float*)d_in[0];
    const float* h2 = (const float*)d_in[1];
    // d_in[2], d_in[3] are batch1/batch2 (unused: equal-sized sorted segments)
    const float* W1 = (const float*)d_in[4];
    const float* b1 = (const float*)d_in[5];
    const float* W2 = (const float*)d_in[6];
    const float* b2 = (const float*)d_in[7];
    float* out = (float*)d_out;

    hipLaunchKernelGGL(ddi_fused, dim3(BB), dim3(NT), 0, stream,
                       h1, h2, W1, b1, W2, b2, out);
}

// Round 4
// 27.359 us; speedup vs baseline: 1.3620x; 1.2149x over previous
//
#include <hip/hip_runtime.h>

#define BB 256      // drug pairs
#define NP 40       // atoms per graph
#define HH 128      // hidden dim
#define EST 132     // E-array row stride (floats); 528B, 16B-aligned
#define SST 44      // sE row stride (floats); breaks col-sum bank pattern
#define NT 1024

// w0/d0 + w1/d1 = (w0*d1 + w1*d0) * rcp(d0*d1)  -- one trans per 2 elems
#define BATCH2(acc, ex0, ex1, ey0, ey1, ww0, ww1) do {            \
    float d0_ = fmaf((ex0), (ey0), 1.f);                          \
    float d1_ = fmaf((ex1), (ey1), 1.f);                          \
    float r_  = __builtin_amdgcn_rcpf(d0_ * d1_);                 \
    float n_  = fmaf((ww1), d0_, (ww0) * d1_);                    \
    acc = fmaf(n_, r_, acc);                                      \
} while (0)

__global__ __launch_bounds__(NT) void ddi_fused(
    const float* __restrict__ h1, const float* __restrict__ h2,
    const float* __restrict__ W1, const float* __restrict__ b1,
    const float* __restrict__ W2, const float* __restrict__ b2,
    float* __restrict__ out)
{
    const int b = blockIdx.x;
    const int t = threadIdx.x;

    __shared__ __align__(16) float sA[2*NP*HH];     // 40960 B: A1, A2
    __shared__ __align__(16) float sEE[2*NP*EST];   // 42240 B: E1, E2
    __shared__ __align__(16) float sSE[NP*SST];     // 7040 B: unnormalized probs
    __shared__ __align__(16) float sW2[HH];         // 512 B
    __shared__ float sRed[NT/64];
    __shared__ float sCL;   // (b2 + sum(w2)) * log2(e)
    __shared__ float sRZ;   // 1/Z

    float* sA1 = sA;  float* sA2 = sA + NP*HH;
    float* sE1 = sEE; float* sE2 = sEE + NP*EST;

    const float L2E = 1.44269504088896340736f;
    const float K   = 2.88539008177792681472f;   // 2*log2(e)

    // ---- Phase 0: stage A tiles + w2 + CL ----
    const float4* g1 = (const float4*)(h1 + (size_t)b * NP * HH);
    const float4* g2 = (const float4*)(h2 + (size_t)b * NP * HH);
    for (int idx = t; idx < NP*HH/4; idx += NT) {
        ((float4*)sA1)[idx] = g1[idx];
        ((float4*)sA2)[idx] = g2[idx];
    }
    if (t < HH) sW2[t] = W2[t];
    if (t < 64) {   // wave 0: CL = (b2 + sum(w2)) * log2e
        float c = W2[t] + W2[t + 64];
        #pragma unroll
        for (int off = 32; off > 0; off >>= 1) c += __shfl_down(c, off, 64);
        if (t == 0) sCL = (c + b2[0]) * L2E;
    }
    __syncthreads();

    // ---- Phase 1 (t<512): P = A @ W1-half; store E = exp2(K*(P[+b1])) ----
    // thread -> (matrix m, row-group rh of 10, lane-col hl; owns cols hl, hl+64)
    if (t < 512) {
        const int m  = t >> 8;
        const int rh = (t >> 6) & 3;
        const int hl = t & 63;
        const int r0 = rh * 10;
        const float* Asrc = m ? sA2 : sA1;
        const float* Wc   = W1 + (size_t)m * HH * HH + hl;

        float acc0[10], acc1[10];
        #pragma unroll
        for (int r = 0; r < 10; ++r) { acc0[r] = 0.f; acc1[r] = 0.f; }

        float wc0[4], wc1[4], wn0[4], wn1[4];
        #pragma unroll
        for (int k = 0; k < 4; ++k) { wc0[k] = Wc[k*HH]; wc1[k] = Wc[k*HH + 64]; }
        for (int d0 = 0; d0 < HH; d0 += 4) {
            if (d0 + 4 < HH) {
                #pragma unroll
                for (int k = 0; k < 4; ++k) {
                    wn0[k] = Wc[(d0+4+k)*HH];
                    wn1[k] = Wc[(d0+4+k)*HH + 64];
                }
            }
            #pragma unroll
            for (int r = 0; r < 10; ++r) {
                float4 a = *(const float4*)(Asrc + (r0+r)*HH + d0);  // wave-uniform: broadcast
                acc0[r] = fmaf(a.x, wc0[0], acc0[r]);
                acc0[r] = fmaf(a.y, wc0[1], acc0[r]);
                acc0[r] = fmaf(a.z, wc0[2], acc0[r]);
                acc0[r] = fmaf(a.w, wc0[3], acc0[r]);
                acc1[r] = fmaf(a.x, wc1[0], acc1[r]);
                acc1[r] = fmaf(a.y, wc1[1], acc1[r]);
                acc1[r] = fmaf(a.z, wc1[2], acc1[r]);
                acc1[r] = fmaf(a.w, wc1[3], acc1[r]);
            }
            #pragma unroll
            for (int k = 0; k < 4; ++k) { wc0[k] = wn0[k]; wc1[k] = wn1[k]; }
        }
        const float bh0 = m ? 0.f : b1[hl];
        const float bh1 = m ? 0.f : b1[hl + 64];
        float* Ed = m ? sE2 : sE1;
        #pragma unroll
        for (int r = 0; r < 10; ++r) {
            Ed[(r0+r)*EST + hl]      = __builtin_amdgcn_exp2f(K * (acc0[r] + bh0));
            Ed[(r0+r)*EST + hl + 64] = __builtin_amdgcn_exp2f(K * (acc1[r] + bh1));
        }
    }
    __syncthreads();

    // ---- Phase 2 (t<800): 2x2 pair tile x h-half; tanh = 1 - 2/(E1*E2+1) ----
    float lsum = 0.f;
    if (t < 800) {
        const int tile = t >> 1;         // 400 tiles
        const int half = t & 1;          // h-half; lanes (even,odd) share a tile
        const int it = tile / 20;
        const int jt = tile - it * 20;
        const int h0 = half << 6;
        const float* x1a = sE1 + it*EST + h0;        // rows it, it+20 (<=2 distinct/wave)
        const float* x1b = x1a + 20*EST;
        const float* y2a = sE2 + jt*EST + h0;        // rows jt, jt+20
        const float* y2b = y2a + 20*EST;
        const float* wp  = sW2 + h0;
        float a00 = 0.f, a01 = 0.f, a10 = 0.f, a11 = 0.f;
        #pragma unroll 4
        for (int s = 0; s < 64; s += 4) {
            float4 ea = *(const float4*)(x1a + s);
            float4 eb = *(const float4*)(x1b + s);
            float4 fa = *(const float4*)(y2a + s);
            float4 fb = *(const float4*)(y2b + s);
            float4 wv = *(const float4*)(wp  + s);
            BATCH2(a00, ea.x, ea.y, fa.x, fa.y, wv.x, wv.y);
            BATCH2(a00, ea.z, ea.w, fa.z, fa.w, wv.z, wv.w);
            BATCH2(a01, ea.x, ea.y, fb.x, fb.y, wv.x, wv.y);
            BATCH2(a01, ea.z, ea.w, fb.z, fb.w, wv.z, wv.w);
            BATCH2(a10, eb.x, eb.y, fa.x, fa.y, wv.x, wv.y);
            BATCH2(a10, eb.z, eb.w, fa.z, fa.w, wv.z, wv.w);
            BATCH2(a11, eb.x, eb.y, fb.x, fb.y, wv.x, wv.y);
            BATCH2(a11, eb.z, eb.w, fb.z, fb.w, wv.z, wv.w);
        }
        // combine h-halves: even/odd lanes hold complementary halves of same tile
        a00 += __shfl_xor(a00, 1);
        a01 += __shfl_xor(a01, 1);
        a10 += __shfl_xor(a10, 1);
        a11 += __shfl_xor(a11, 1);
        // logit = C - 2*acc; pu = exp2(CL - K*acc). even lane: row it; odd: it+20
        const float CL = sCL;
        const int iRow = it + 20 * half;
        const float accA = half ? a10 : a00;
        const float accB = half ? a11 : a01;
        float puA = __builtin_amdgcn_exp2f(fmaf(accA, -K, CL));
        float puB = __builtin_amdgcn_exp2f(fmaf(accB, -K, CL));
        sSE[iRow*SST + jt]      = puA;
        sSE[iRow*SST + jt + 20] = puB;
        lsum = puA + puB;
    }

    // ---- block reduction for Z ----
    #pragma unroll
    for (int off = 32; off > 0; off >>= 1) lsum += __shfl_down(lsum, off, 64);
    if ((t & 63) == 0) sRed[t >> 6] = lsum;
    __syncthreads();
    if (t == 0) {
        float Z = 0.f;
        #pragma unroll
        for (int wv = 0; wv < NT/64; ++wv) Z += sRed[wv];
        sRZ = 1.0f / Z;
    }
    __syncthreads();
    const float rZ = sRZ;

    // ---- Phase 3: parallel row/col sums (8 lanes each, width-8 shuffle) ----
    if (t < 320) {
        const int row = t >> 3, seg = t & 7;
        const float* p = sSE + row*SST + seg*5;
        float s = p[0] + p[1] + p[2] + p[3] + p[4];
        s += __shfl_down(s, 4, 8);
        s += __shfl_down(s, 2, 8);
        s += __shfl_down(s, 1, 8);
        if (seg == 0) out[b*NP + row] = s * rZ;
    } else if (t < 640) {
        const int q = t - 320;
        const int col = q >> 3, seg = q & 7;
        float s = 0.f;
        #pragma unroll
        for (int k = 0; k < 5; ++k) s += sSE[(seg*5 + k)*SST + col];
        s += __shfl_down(s, 4, 8);
        s += __shfl_down(s, 2, 8);
        s += __shfl_down(s, 1, 8);
        if (seg == 0) out[BB*NP + b*NP + col] = s * rZ;
    }
}

extern "C" void kernel_launch(void* const* d_in, const int* in_sizes, int n_in,
                              void* d_out, int out_size, void* d_ws, size_t ws_size,
                              hipStream_t stream) {
    const float* h1 = (const float*)d_in[0];
    const float* h2 = (const float*)d_in[1];
    // d_in[2], d_in[3] are batch1/batch2 (unused: equal-sized sorted segments)
    const float* W1 = (const float*)d_in[4];
    const float* b1 = (const float*)d_in[5];
    const float* W2 = (const float*)d_in[6];
    const float* b2 = (const float*)d_in[7];
    float* out = (float*)d_out;

    hipLaunchKernelGGL(ddi_fused, dim3(BB), dim3(NT), 0, stream,
                       h1, h2, W1, b1, W2, b2, out);
}

// Round 5
// 17.494 us; speedup vs baseline: 2.1300x; 1.5640x over previous
//
#include <hip/hip_runtime.h>

#define BB 256      // drug pairs
#define NP 40       // atoms per graph
#define HH 128      // hidden dim
#define EST 132     // E row stride (floats); 528B = 33*16, breaks bank alignment
#define SST 44      // sSE row stride
#define NT 1024
#define AROWB 272   // bf16-A LDS row stride in bytes (256 + 16 pad)
#define NROWP 48    // A rows padded to 3 MFMA tiles

typedef __attribute__((ext_vector_type(8))) short bf16x8;
typedef __attribute__((ext_vector_type(4))) float f32x4;

static __device__ __forceinline__ unsigned short f2bf(float f) {
    unsigned u = __float_as_uint(f);                     // RTNE fp32 -> bf16
    return (unsigned short)((u + 0x7FFFu + ((u >> 16) & 1u)) >> 16);
}

// w0/d0 + w1/d1 = (w0*d1 + w1*d0) * rcp(d0*d1)  -- one trans per 2 elems
#define BATCH2(acc, ex0, ex1, ey0, ey1, ww0, ww1) do {            \
    float d0_ = fmaf((ex0), (ey0), 1.f);                          \
    float d1_ = fmaf((ex1), (ey1), 1.f);                          \
    float r_  = __builtin_amdgcn_rcpf(d0_ * d1_);                 \
    float n_  = fmaf((ww1), d0_, (ww0) * d1_);                    \
    acc = fmaf(n_, r_, acc);                                      \
} while (0)

__global__ __launch_bounds__(NT) void ddi_fused(
    const float* __restrict__ h1, const float* __restrict__ h2,
    const float* __restrict__ W1, const float* __restrict__ b1,
    const float* __restrict__ W2, const float* __restrict__ b2,
    float* __restrict__ out)
{
    const int b = blockIdx.x;
    const int t = threadIdx.x;
    const int l = t & 63;
    const int w = t >> 6;

    __shared__ __align__(16) char  sAB[2*NROWP*AROWB];   // 26112 B: bf16 A1,A2 (rows 40-47 zero)
    __shared__ __align__(16) float sE[2*(NP+1)*EST];     // 43296 B: E1,E2 (+1 dump row each)
    __shared__ __align__(16) float sSE[NP*SST];          // 7040 B
    __shared__ __align__(16) float sW2[HH];
    __shared__ __align__(16) float sKB1[HH];             // K * b1
    __shared__ float sRed[NT/64];
    __shared__ float sCL, sRZ;

    const float L2E = 1.44269504088896340736f;
    const float K   = 2.88539008177792681472f;   // 2*log2(e)

    // ---- W1 fragment loads (global, issued first; A-operand = W^T) ----
    // wave w -> (matrix m, h-tile hm). lane l: A-op row h = hm*16 + (l&15),
    // k = ks*32 + (l>>4)*8 + j  ->  W1[(m*128 + k)*128 + h]
    const int m  = w >> 3;
    const int hm = w & 7;
    const float* Wb = W1 + (size_t)m*HH*HH + hm*16 + (l & 15);
    float wraw[4][8];
    #pragma unroll
    for (int ks = 0; ks < 4; ++ks)
        #pragma unroll
        for (int j = 0; j < 8; ++j)
            wraw[ks][j] = Wb[(size_t)(ks*32 + ((l>>4)<<3) + j) * HH];

    // ---- stage A as bf16 into padded LDS (1536 slots of 16B) ----
    #pragma unroll
    for (int pass = 0; pass < 2; ++pass) {
        int s = t + pass*NT;
        if (s < 2*NROWP*16) {
            int ms  = (s >= NROWP*16) ? 1 : 0;
            int rem = s - ms*NROWP*16;
            int r   = rem >> 4;
            int kg  = rem & 15;
            float4 v0 = make_float4(0.f,0.f,0.f,0.f), v1 = v0;
            if (r < NP) {
                const float* src = (ms ? h2 : h1) + ((size_t)b*NP + r)*HH + kg*8;
                v0 = *(const float4*)src;
                v1 = *(const float4*)(src + 4);
            }
            unsigned p0 = f2bf(v0.x) | ((unsigned)f2bf(v0.y) << 16);
            unsigned p1 = f2bf(v0.z) | ((unsigned)f2bf(v0.w) << 16);
            unsigned p2 = f2bf(v1.x) | ((unsigned)f2bf(v1.y) << 16);
            unsigned p3 = f2bf(v1.z) | ((unsigned)f2bf(v1.w) << 16);
            *(uint4*)(sAB + (ms*NROWP + r)*AROWB + kg*16) = make_uint4(p0,p1,p2,p3);
        }
    }
    if (t < HH) { sW2[t] = W2[t]; sKB1[t] = K * b1[t]; }
    if (t < 64) {   // CL = (b2 + sum(w2)) * log2e
        float c = W2[t] + W2[t + 64];
        #pragma unroll
        for (int off = 32; off > 0; off >>= 1) c += __shfl_down(c, off, 64);
        if (t == 0) sCL = (c + b2[0]) * L2E;
    }

    // convert W fragments while staging drains
    bf16x8 wf[4];
    #pragma unroll
    for (int ks = 0; ks < 4; ++ks) {
        #pragma unroll
        for (int j = 0; j < 8; ++j)
            ((unsigned short*)&wf[ks])[j] = f2bf(wraw[ks][j]);
    }
    __syncthreads();

    // ---- MFMA: P^T(16h x 16r) = W^T * A^T over 4 k-slices; E = exp2(K*P + K*b1) ----
    {
        const char* Ab = sAB + (m*NROWP + (l & 15))*AROWB + ((l >> 4) << 4);
        const int hbase = hm*16 + ((l >> 4) << 2);
        float4 kb = make_float4(0.f,0.f,0.f,0.f);
        if (m == 0) kb = *(const float4*)(sKB1 + hbase);
        #pragma unroll
        for (int rn = 0; rn < 3; ++rn) {
            f32x4 c = {0.f, 0.f, 0.f, 0.f};
            #pragma unroll
            for (int ks = 0; ks < 4; ++ks) {
                bf16x8 af = *(const bf16x8*)(Ab + rn*(16*AROWB) + ks*64);
                c = __builtin_amdgcn_mfma_f32_16x16x32_bf16(wf[ks], af, c, 0, 0, 0);
            }
            int r   = rn*16 + (l & 15);
            int row = (r < NP) ? r : NP;   // rows 40-47 -> dump row
            float4 ev;
            ev.x = __builtin_amdgcn_exp2f(fmaf(K, c[0], kb.x));
            ev.y = __builtin_amdgcn_exp2f(fmaf(K, c[1], kb.y));
            ev.z = __builtin_amdgcn_exp2f(fmaf(K, c[2], kb.z));
            ev.w = __builtin_amdgcn_exp2f(fmaf(K, c[3], kb.w));
            *(float4*)(sE + (m*(NP+1) + row)*EST + hbase) = ev;
        }
    }
    __syncthreads();

    // ---- Phase 2: 2x2 pair tile x h-half; tanh = 1 - 2/(E1*E2+1) ----
    float lsum = 0.f;
    if (t < 800) {
        const int tile = t >> 1;
        const int half = t & 1;
        const int it = tile / 20;
        const int jt = tile - it * 20;
        const int h0 = half << 6;
        const float* x1a = sE + it*EST + h0;               // E1 rows it, it+20
        const float* x1b = x1a + 20*EST;
        const float* y2a = sE + (NP+1 + jt)*EST + h0;      // E2 rows jt, jt+20
        const float* y2b = y2a + 20*EST;
        const float* wp  = sW2 + h0;
        float a00 = 0.f, a01 = 0.f, a10 = 0.f, a11 = 0.f;
        #pragma unroll 4
        for (int s = 0; s < 64; s += 4) {
            float4 ea = *(const float4*)(x1a + s);
            float4 eb = *(const float4*)(x1b + s);
            float4 fa = *(const float4*)(y2a + s);
            float4 fb = *(const float4*)(y2b + s);
            float4 wv = *(const float4*)(wp  + s);
            BATCH2(a00, ea.x, ea.y, fa.x, fa.y, wv.x, wv.y);
            BATCH2(a00, ea.z, ea.w, fa.z, fa.w, wv.z, wv.w);
            BATCH2(a01, ea.x, ea.y, fb.x, fb.y, wv.x, wv.y);
            BATCH2(a01, ea.z, ea.w, fb.z, fb.w, wv.z, wv.w);
            BATCH2(a10, eb.x, eb.y, fa.x, fa.y, wv.x, wv.y);
            BATCH2(a10, eb.z, eb.w, fa.z, fa.w, wv.z, wv.w);
            BATCH2(a11, eb.x, eb.y, fb.x, fb.y, wv.x, wv.y);
            BATCH2(a11, eb.z, eb.w, fb.z, fb.w, wv.z, wv.w);
        }
        a00 += __shfl_xor(a00, 1);
        a01 += __shfl_xor(a01, 1);
        a10 += __shfl_xor(a10, 1);
        a11 += __shfl_xor(a11, 1);
        const float CL = sCL;
        const int iRow = it + 20 * half;
        const float accA = half ? a10 : a00;
        const float accB = half ? a11 : a01;
        float puA = __builtin_amdgcn_exp2f(fmaf(accA, -K, CL));
        float puB = __builtin_amdgcn_exp2f(fmaf(accB, -K, CL));
        sSE[iRow*SST + jt]      = puA;
        sSE[iRow*SST + jt + 20] = puB;
        lsum = puA + puB;
    }

    // ---- block reduction for Z ----
    #pragma unroll
    for (int off = 32; off > 0; off >>= 1) lsum += __shfl_down(lsum, off, 64);
    if ((t & 63) == 0) sRed[t >> 6] = lsum;
    __syncthreads();
    if (t == 0) {
        float Z = 0.f;
        #pragma unroll
        for (int wv = 0; wv < NT/64; ++wv) Z += sRed[wv];
        sRZ = 1.0f / Z;
    }
    __syncthreads();
    const float rZ = sRZ;

    // ---- Phase 3: parallel row/col sums ----
    if (t < 320) {
        const int row = t >> 3, seg = t & 7;
        const float* p = sSE + row*SST + seg*5;
        float s = p[0] + p[1] + p[2] + p[3] + p[4];
        s += __shfl_down(s, 4, 8);
        s += __shfl_down(s, 2, 8);
        s += __shfl_down(s, 1, 8);
        if (seg == 0) out[b*NP + row] = s * rZ;
    } else if (t < 640) {
        const int q = t - 320;
        const int col = q >> 3, seg = q & 7;
        float s = 0.f;
        #pragma unroll
        for (int k = 0; k < 5; ++k) s += sSE[(seg*5 + k)*SST + col];
        s += __shfl_down(s, 4, 8);
        s += __shfl_down(s, 2, 8);
        s += __shfl_down(s, 1, 8);
        if (seg == 0) out[BB*NP + b*NP + col] = s * rZ;
    }
}

extern "C" void kernel_launch(void* const* d_in, const int* in_sizes, int n_in,
                              void* d_out, int out_size, void* d_ws, size_t ws_size,
                              hipStream_t stream) {
    const float* h1 = (const float*)d_in[0];
    const float* h2 = (const float*)d_in[1];
    // d_in[2], d_in[3] are batch1/batch2 (unused: equal-sized sorted segments)
    const float* W1 = (const float*)d_in[4];
    const float* b1 = (const float*)d_in[5];
    const float* W2 = (const float*)d_in[6];
    const float* b2 = (const float*)d_in[7];
    float* out = (float*)d_out;

    hipLaunchKernelGGL(ddi_fused, dim3(BB), dim3(NT), 0, stream,
                       h1, h2, W1, b1, W2, b2, out);
}